// Round 10
// baseline (257.718 us; speedup 1.0000x reference)
//
#include <hip/hip_runtime.h>

#define RES   256
#define NCH   128   // C*F
#define NC    16
#define QG    32    // channels per transpose block
#define NPK   64    // packed uint32 per (p,y,x) position = NCH/2

typedef float fx4 __attribute__((ext_vector_type(4)));   // native vec for NT builtins

__device__ __forceinline__ unsigned int f32_to_bf16_rne(float f) {
    unsigned int u = __float_as_uint(f);
    return (u + 0x7FFFu + ((u >> 16) & 1u)) >> 16;
}
__device__ __forceinline__ float bf16_lo(unsigned int w) {
    return __uint_as_float(w << 16);
}
__device__ __forceinline__ float bf16_hi(unsigned int w) {
    return __uint_as_float(w & 0xFFFF0000u);
}
__device__ __forceinline__ float reflectf(float v) {
    float r = fabsf(v);
    r = fmodf(r, 510.0f);                 // m = 2*(RES-1)
    return (r > 255.0f) ? (510.0f - r) : r;
}

// ---------------------------------------------------------------------------
// Transpose+pack f32 [3][128][256][256] -> bf16-pair uint32 [3][256][256][64]
// (channel-minor — r6 proved load-bearing). r3-exact structure: NT f32 loads
// (grid read once per iter), LDS pack-early (16.6KB), CACHED uint4 stores
// (r9 proved main depends on gridT being L2/L3-resident).
// v10: Morton histogram REMOVED (sort chain dropped); frp precompute fused
// into block (0,0,0).
// ---------------------------------------------------------------------------
__global__ __launch_bounds__(256) void fg_transpose(
    const float* __restrict__ in, unsigned int* __restrict__ out,
    const float* __restrict__ freqs, float* __restrict__ frp)
{
    __shared__ unsigned int tile[QG / 2][RES + 4];   // packed bf16-pairs, stride 260 words
    const int tid = threadIdx.x;
    const int qg = blockIdx.x;            // 0..3
    const int y  = blockIdx.y;            // 0..255
    const int p  = blockIdx.z;            // 0..2

    if (qg == 0 && y == 0 && p == 0 && tid < 128) {
        const float f = fminf(fmaxf(freqs[tid], 0.0f), 1.0f);
        frp[tid] = __builtin_amdgcn_exp2f(f * 8.0f) - 0.5f;
    }

    const int q0 = qg * QG;
    const float* src = in + (((size_t)p * NCH + q0) * RES + y) * RES;
    #pragma unroll
    for (int it = 0; it < 4; ++it) {       // 16 pair-rows x 64 float4-cols
        const int lin = it * 256 + tid;    // 0..1023
        const int k   = lin >> 6;          // pair row within group (0..15)
        const int x4  = lin & 63;          // float4 index within row
        const fx4 a = __builtin_nontemporal_load(
            (const fx4*)(src + (size_t)(2 * k + 0) * (RES * RES) + x4 * 4));
        const fx4 b = __builtin_nontemporal_load(
            (const fx4*)(src + (size_t)(2 * k + 1) * (RES * RES) + x4 * 4));
        uint4 w;
        w.x = f32_to_bf16_rne(a.x) | (f32_to_bf16_rne(b.x) << 16);
        w.y = f32_to_bf16_rne(a.y) | (f32_to_bf16_rne(b.y) << 16);
        w.z = f32_to_bf16_rne(a.z) | (f32_to_bf16_rne(b.z) << 16);
        w.w = f32_to_bf16_rne(a.w) | (f32_to_bf16_rne(b.w) << 16);
        *(uint4*)&tile[k][x4 * 4] = w;
    }
    __syncthreads();
    unsigned int* dst = out + (((size_t)p * RES + y) * RES) * NPK + (q0 >> 1);
    #pragma unroll
    for (int it = 0; it < 4; ++it) {       // 256 x-cols x 4 uint4-groups
        const int lin = it * 256 + tid;    // 0..1023
        const int q4 = lin & 3;            // uint4 group within the 16 pairs
        const int x  = lin >> 2;           // x column 0..255
        uint4 w;
        w.x = tile[4 * q4 + 0][x];
        w.y = tile[4 * q4 + 1][x];
        w.z = tile[4 * q4 + 2][x];
        w.w = tile[4 * q4 + 3][x];
        *(uint4*)&dst[(size_t)x * NPK + q4 * 4] = w;   // CACHED: main re-reads
    }
}

// ---------------------------------------------------------------------------
// Main kernel v10: UNSORTED (sort chain removed). Rationale: main is
// VALU-bound (VALUBusy ~90%, HBM 22%) and gridT (50MB) fits L3 5x over, so
// L2-locality from the Morton sort is not on the critical path; the chain
// cost (memset+scan+scatter ~11us + 3 dispatch gaps) is.
// Structure otherwise = r3 best: per-plane setup, all 12 gathers hoisted,
// NT store of out.
// ---------------------------------------------------------------------------
__global__ __launch_bounds__(256) void fg_main_bf16(
    const unsigned int* __restrict__ grid,   // [3][256][256][64]
    const float* __restrict__ frp_in,        // 128 precomputed (fr+0.5)
    const float* __restrict__ coords,
    float* __restrict__ out, int n)
{
    const int t = threadIdx.x;
    const int c = t & 15;                        // output channel 0..15
    const int i = blockIdx.x * 16 + (t >> 4);    // point index (original order)
    if (i >= n) return;

    const float c0 = coords[3 * (size_t)i + 0];  // 16 lanes broadcast 12B
    const float c1 = coords[3 * (size_t)i + 1];
    const float c2 = coords[3 * (size_t)i + 2];
    const float pts0 = (c0 + 1.0f) * 127.5f;
    const float pts1 = (c1 + 1.0f) * 127.5f;
    const float pts2 = (c2 + 1.0f) * 127.5f;

    float frp[8];
    *(float4*)(frp + 0) = *(const float4*)(frp_in + c * 8 + 0);
    *(float4*)(frp + 4) = *(const float4*)(frp_in + c * 8 + 4);

    float Aa[3], W00[3], W01[3], W10[3], W11[3];
    uint4 g[3][4];

    #pragma unroll
    for (int p = 0; p < 3; ++p) {
        // plane 0 samples (y,z); plane 1 (x,z); plane 2 (x,y)
        const float sx = (p == 0) ? pts1 : pts0;
        const float sy = (p == 2) ? pts1 : pts2;
        const float pp = (p == 0) ? pts0 : ((p == 1) ? pts1 : pts2);

        const float ix = reflectf(sx);
        const float iy = reflectf(sy);
        const float x0f = floorf(ix), y0f = floorf(iy);
        const float wx = ix - x0f, wy = iy - y0f;
        int x0 = (int)x0f; x0 = min(max(x0, 0), RES - 1);
        int y0 = (int)y0f; y0 = min(max(y0, 0), RES - 1);
        const int x1 = min(x0 + 1, RES - 1);
        const int y1 = min(y0 + 1, RES - 1);
        W00[p] = (1.0f - wx) * (1.0f - wy);
        W01[p] = wx * (1.0f - wy);
        W10[p] = (1.0f - wx) * wy;
        W11[p] = wx * wy;
        // phase in revolutions: (pts+0.5)*(fr+0.5)/512 -> v_cos(2*pi*rev)
        Aa[p] = (pp + 0.5f) * (1.0f / 512.0f);

        const int rowbase = p * (RES * RES);
        const int o00 = (rowbase + y0 * RES + x0) * NPK + c * 4;
        const int o01 = (rowbase + y0 * RES + x1) * NPK + c * 4;
        const int o10 = (rowbase + y1 * RES + x0) * NPK + c * 4;
        const int o11 = (rowbase + y1 * RES + x1) * NPK + c * 4;
        g[p][0] = *(const uint4*)(grid + o00);
        g[p][1] = *(const uint4*)(grid + o01);
        g[p][2] = *(const uint4*)(grid + o10);
        g[p][3] = *(const uint4*)(grid + o11);
    }

    float acc = 0.0f;
    #pragma unroll
    for (int p = 0; p < 3; ++p) {
        const unsigned int w0[4] = {g[p][0].x, g[p][0].y, g[p][0].z, g[p][0].w};
        const unsigned int w1[4] = {g[p][1].x, g[p][1].y, g[p][1].z, g[p][1].w};
        const unsigned int w2[4] = {g[p][2].x, g[p][2].y, g[p][2].z, g[p][2].w};
        const unsigned int w3[4] = {g[p][3].x, g[p][3].y, g[p][3].z, g[p][3].w};
        const float w00 = W00[p], w01 = W01[p], w10 = W10[p], w11 = W11[p];
        const float A = Aa[p];

        #pragma unroll
        for (int jj = 0; jj < 4; ++jj) {
            const float clo = w00 * bf16_lo(w0[jj]) + w01 * bf16_lo(w1[jj])
                            + w10 * bf16_lo(w2[jj]) + w11 * bf16_lo(w3[jj]);
            const float chi = w00 * bf16_hi(w0[jj]) + w01 * bf16_hi(w1[jj])
                            + w10 * bf16_hi(w2[jj]) + w11 * bf16_hi(w3[jj]);
            const float rl = __builtin_amdgcn_fractf(A * frp[2 * jj + 0]);
            const float rh = __builtin_amdgcn_fractf(A * frp[2 * jj + 1]);
            acc += clo * __builtin_amdgcn_cosf(rl);
            acc += chi * __builtin_amdgcn_cosf(rh);
        }
    }

    __builtin_nontemporal_store(2.0f * acc, &out[(size_t)i * NC + c]);
}

// Fallback (no workspace): direct f32 channel-major gather.
__global__ __launch_bounds__(256) void fg_main_f32(
    const float* __restrict__ coords,
    const float* __restrict__ grid,
    const float* __restrict__ freqs,
    float* __restrict__ out, int n)
{
    const int t = threadIdx.x;
    const int c = t & 15;
    const int i = blockIdx.x * 16 + (t >> 4);
    if (i >= n) return;

    float frp[8];
    #pragma unroll
    for (int j = 0; j < 8; ++j) {
        float f = fminf(fmaxf(freqs[c * 8 + j], 0.0f), 1.0f);
        frp[j] = __builtin_amdgcn_exp2f(f * 8.0f) - 0.5f;
    }
    const float c0 = coords[3 * (size_t)i + 0];
    const float c1 = coords[3 * (size_t)i + 1];
    const float c2 = coords[3 * (size_t)i + 2];
    const float pts0 = (c0 + 1.0f) * 127.5f;
    const float pts1 = (c1 + 1.0f) * 127.5f;
    const float pts2 = (c2 + 1.0f) * 127.5f;
    float acc = 0.0f;
    #pragma unroll
    for (int p = 0; p < 3; ++p) {
        const float sx = (p == 0) ? pts1 : pts0;
        const float sy = (p == 2) ? pts1 : pts2;
        const float pp = (p == 0) ? pts0 : ((p == 1) ? pts1 : pts2);
        const float ix = reflectf(sx);
        const float iy = reflectf(sy);
        const float x0f = floorf(ix), y0f = floorf(iy);
        const float wx = ix - x0f, wy = iy - y0f;
        int x0 = (int)x0f; x0 = min(max(x0, 0), RES - 1);
        int y0 = (int)y0f; y0 = min(max(y0, 0), RES - 1);
        const int x1 = min(x0 + 1, RES - 1);
        const int y1 = min(y0 + 1, RES - 1);
        const float w00 = (1.0f - wx) * (1.0f - wy);
        const float w01 = wx * (1.0f - wy);
        const float w10 = (1.0f - wx) * wy;
        const float w11 = wx * wy;
        const float A = (pp + 0.5f) * (1.0f / 512.0f);
        const size_t plane = (size_t)p * NCH * RES * RES;
        const int o00 = y0 * RES + x0, o01 = y0 * RES + x1;
        const int o10 = y1 * RES + x0, o11 = y1 * RES + x1;
        #pragma unroll
        for (int j = 0; j < 8; ++j) {
            const float* gq = grid + plane + (size_t)(c * 8 + j) * (RES * RES);
            const float coef = w00 * gq[o00] + w01 * gq[o01]
                             + w10 * gq[o10] + w11 * gq[o11];
            const float rr = __builtin_amdgcn_fractf(A * frp[j]);
            acc += coef * __builtin_amdgcn_cosf(rr);
        }
    }
    out[(size_t)i * NC + c] = 2.0f * acc;
}

extern "C" void kernel_launch(void* const* d_in, const int* in_sizes, int n_in,
                              void* d_out, int out_size, void* d_ws, size_t ws_size,
                              hipStream_t stream)
{
    const float* coords = (const float*)d_in[0];
    const float* grid   = (const float*)d_in[1];
    const float* freqs  = (const float*)d_in[2];
    float* out = (float*)d_out;
    const int n = in_sizes[0] / 3;

    // Workspace layout (16B-aligned)
    const size_t gridT_b  = (size_t)3 * RES * RES * NPK * sizeof(unsigned); // 50.33 MB
    const size_t frp_b    = 128 * sizeof(float);
    const size_t need = gridT_b + frp_b;

    const int blocks = (n + 15) / 16;

    if (ws_size >= need) {
        char* ws = (char*)d_ws;
        unsigned* gridT = (unsigned*)ws;                  ws += gridT_b;
        float*    frp   = (float*)ws;

        hipLaunchKernelGGL(fg_transpose, dim3(4, RES, 3), dim3(256), 0, stream,
                           grid, gridT, freqs, frp);
        hipLaunchKernelGGL(fg_main_bf16, dim3(blocks), dim3(256), 0, stream,
                           gridT, frp, coords, out, n);
    } else {
        hipLaunchKernelGGL(fg_main_f32, dim3(blocks), dim3(256), 0, stream,
                           coords, grid, freqs, out, n);
    }
}

// Round 11
// 239.380 us; speedup vs baseline: 1.0766x; 1.0766x over previous
//
#include <hip/hip_runtime.h>

#define RES   256
#define NCH   128   // C*F
#define NC    16
#define QG    32    // channels per transpose block
#define NPK   64    // packed uint32 per (p,y,x) position = NCH/2
#define NBINS 4096  // 16^3 Morton cells
#define TBLK  3072  // transpose grid size (4*256*3)

typedef float  fx4 __attribute__((ext_vector_type(4)));   // native vec for NT builtins

__device__ __forceinline__ unsigned int f32_to_bf16_rne(float f) {
    unsigned int u = __float_as_uint(f);
    return (u + 0x7FFFu + ((u >> 16) & 1u)) >> 16;
}
__device__ __forceinline__ float bf16_lo(unsigned int w) {
    return __uint_as_float(w << 16);
}
__device__ __forceinline__ float bf16_hi(unsigned int w) {
    return __uint_as_float(w & 0xFFFF0000u);
}
__device__ __forceinline__ float reflectf(float v) {
    float r = fabsf(v);
    r = fmodf(r, 510.0f);                 // m = 2*(RES-1)
    return (r > 255.0f) ? (510.0f - r) : r;
}
__device__ __forceinline__ unsigned spread3(unsigned v) { // 4-bit -> stride-3
    return (v & 1u) | ((v & 2u) << 2) | ((v & 4u) << 4) | ((v & 8u) << 6);
}
__device__ __forceinline__ int point_cell(const float* __restrict__ coords, int i) {
    const float r0 = reflectf((coords[3 * (size_t)i + 0] + 1.0f) * 127.5f);
    const float r1 = reflectf((coords[3 * (size_t)i + 1] + 1.0f) * 127.5f);
    const float r2 = reflectf((coords[3 * (size_t)i + 2] + 1.0f) * 127.5f);
    const unsigned cx = (unsigned)min(max((int)r0, 0), 255) >> 4;
    const unsigned cy = (unsigned)min(max((int)r1, 0), 255) >> 4;
    const unsigned cz = (unsigned)min(max((int)r2, 0), 255) >> 4;
    return (int)(spread3(cx) | (spread3(cy) << 1) | (spread3(cz) << 2));
}

// ---------------------------------------------------------------------------
// Transpose+pack f32 [3][128][256][256] -> bf16-pair uint32 [3][256][256][64]
// (channel-minor layout — r6 proved load-bearing for main's gather locality).
// FUSED with Morton-cell histogram. NT f32 loads (r3 best-measured);
// CACHED stores (r9 proved main depends on gridT being L2/L3-resident).
// ---------------------------------------------------------------------------
__global__ __launch_bounds__(256) void fg_transpose_hist(
    const float* __restrict__ in, unsigned int* __restrict__ out,
    const float* __restrict__ coords, unsigned* __restrict__ hist, int n)
{
    __shared__ unsigned int tile[QG / 2][RES + 4];   // packed bf16-pairs, stride 260 words
    const int tid = threadIdx.x;
    const int qg = blockIdx.x;            // 0..3
    const int y  = blockIdx.y;            // 0..255
    const int p  = blockIdx.z;            // 0..2

    // --- histogram slice for this block ---
    {
        const int bid = (p * RES + y) * 4 + qg;          // 0..3071
        const int per = (n + TBLK - 1) / TBLK;           // 86 for n=262144
        const int s0 = bid * per;
        const int s1 = min(s0 + per, n);
        for (int k = s0 + tid; k < s1; k += 256)
            atomicAdd(&hist[point_cell(coords, k)], 1u);
    }

    const int q0 = qg * QG;
    const float* src = in + (((size_t)p * NCH + q0) * RES + y) * RES;
    #pragma unroll
    for (int it = 0; it < 4; ++it) {       // 16 pair-rows x 64 float4-cols
        const int lin = it * 256 + tid;    // 0..1023
        const int k   = lin >> 6;          // pair row within group (0..15)
        const int x4  = lin & 63;          // float4 index within row
        const fx4 a = __builtin_nontemporal_load(
            (const fx4*)(src + (size_t)(2 * k + 0) * (RES * RES) + x4 * 4));
        const fx4 b = __builtin_nontemporal_load(
            (const fx4*)(src + (size_t)(2 * k + 1) * (RES * RES) + x4 * 4));
        uint4 w;
        w.x = f32_to_bf16_rne(a.x) | (f32_to_bf16_rne(b.x) << 16);
        w.y = f32_to_bf16_rne(a.y) | (f32_to_bf16_rne(b.y) << 16);
        w.z = f32_to_bf16_rne(a.z) | (f32_to_bf16_rne(b.z) << 16);
        w.w = f32_to_bf16_rne(a.w) | (f32_to_bf16_rne(b.w) << 16);
        *(uint4*)&tile[k][x4 * 4] = w;
    }
    __syncthreads();
    unsigned int* dst = out + (((size_t)p * RES + y) * RES) * NPK + (q0 >> 1);
    #pragma unroll
    for (int it = 0; it < 4; ++it) {       // 256 x-cols x 4 uint4-groups
        const int lin = it * 256 + tid;    // 0..1023
        const int q4 = lin & 3;            // uint4 group within the 16 pairs
        const int x  = lin >> 2;           // x column 0..255
        uint4 w;
        w.x = tile[4 * q4 + 0][x];
        w.y = tile[4 * q4 + 1][x];
        w.z = tile[4 * q4 + 2][x];
        w.w = tile[4 * q4 + 3][x];
        *(uint4*)&dst[(size_t)x * NPK + q4 * 4] = w;   // CACHED: main re-reads
    }
}

// ---------------------------------------------------------------------------
// Exclusive scan over 4096 bins (one block, wave-shuffle prefix, 1 barrier)
// + frp precompute
// ---------------------------------------------------------------------------
__global__ __launch_bounds__(256) void fg_scan(
    const unsigned* __restrict__ hist, unsigned* __restrict__ cursor,
    const float* __restrict__ freqs, float* __restrict__ frp)
{
    __shared__ unsigned wtot[4];
    const int t = threadIdx.x;
    const int lane = t & 63;
    const int wid = t >> 6;
    unsigned loc[16];
    unsigned sum = 0;
    #pragma unroll
    for (int k = 0; k < 16; ++k) { loc[k] = hist[t * 16 + k]; sum += loc[k]; }
    unsigned v = sum;
    #pragma unroll
    for (int off = 1; off < 64; off <<= 1) {
        unsigned u = __shfl_up(v, off);
        if (lane >= off) v += u;
    }
    if (lane == 63) wtot[wid] = v;
    __syncthreads();
    unsigned base = 0;
    #pragma unroll
    for (int w = 0; w < 4; ++w) base += (w < wid) ? wtot[w] : 0u;
    unsigned run = base + (v - sum);      // exclusive prefix for this thread
    #pragma unroll
    for (int k = 0; k < 16; ++k) { cursor[t * 16 + k] = run; run += loc[k]; }
    if (t < 128) {
        const float f = fminf(fmaxf(freqs[t], 0.0f), 1.0f);
        frp[t] = __builtin_amdgcn_exp2f(f * 8.0f) - 0.5f;
    }
}

// ---------------------------------------------------------------------------
// Scatter: sort points into Morton order, emitting a 16B RECORD per point:
// {pts0, pts1, pts2, bitcast(original index)} — removes the dependent
// perm->coords pointer chase from main. CACHED store (main re-reads it).
// ---------------------------------------------------------------------------
__global__ __launch_bounds__(256) void fg_scatter(
    const float* __restrict__ coords, unsigned* __restrict__ cursor,
    float4* __restrict__ rec, int n)
{
    const int i = blockIdx.x * 256 + threadIdx.x;
    if (i >= n) return;
    const float c0 = coords[3 * (size_t)i + 0];
    const float c1 = coords[3 * (size_t)i + 1];
    const float c2 = coords[3 * (size_t)i + 2];
    const float p0 = (c0 + 1.0f) * 127.5f;
    const float p1 = (c1 + 1.0f) * 127.5f;
    const float p2 = (c2 + 1.0f) * 127.5f;
    const float r0 = reflectf(p0);
    const float r1 = reflectf(p1);
    const float r2 = reflectf(p2);
    const unsigned cx = (unsigned)min(max((int)r0, 0), 255) >> 4;
    const unsigned cy = (unsigned)min(max((int)r1, 0), 255) >> 4;
    const unsigned cz = (unsigned)min(max((int)r2, 0), 255) >> 4;
    const int cell = (int)(spread3(cx) | (spread3(cy) << 1) | (spread3(cz) << 2));
    const unsigned pos = atomicAdd(&cursor[cell], 1u);
    rec[pos] = make_float4(p0, p1, p2, __uint_as_float((unsigned)i));
}

// ---------------------------------------------------------------------------
// Main kernel (r3 best-measured, 240.8):
//  - Morton-sorted via rec (sort proven load-bearing by r10: FETCH 88->363MB
//    without it)
//  - one broadcast float4 record, no pointer chase
//  - all 12 grid gathers issued before any trig/interp consumes them
//  - XCD-chunk swizzle for L2 locality
//  - NT store for out (write-once)
// VALU-bound at ~90% VALUBusy (r4) — at its instruction floor.
// ---------------------------------------------------------------------------
__global__ __launch_bounds__(256) void fg_main_bf16(
    const unsigned int* __restrict__ grid,   // [3][256][256][64]
    const float* __restrict__ frp_in,        // 128 precomputed (fr+0.5)
    const float4* __restrict__ rec,
    float* __restrict__ out, int n)
{
    const int t = threadIdx.x;
    const int c = t & 15;                        // output channel 0..15
    int b = blockIdx.x;
    {
        const int G = gridDim.x;
        const int chunk = G >> 3;
        const int lim = chunk << 3;
        if (b < lim) b = (b & 7) * chunk + (b >> 3);  // undo round-robin
    }
    const int slot = b * 16 + (t >> 4);          // sorted slot
    if (slot >= n) return;
    const float4 r = rec[slot];                  // 16 lanes broadcast same 16B
    const int i = (int)__float_as_uint(r.w);     // original point index

    float frp[8];
    *(float4*)(frp + 0) = *(const float4*)(frp_in + c * 8 + 0);
    *(float4*)(frp + 4) = *(const float4*)(frp_in + c * 8 + 4);

    const float pts0 = r.x;
    const float pts1 = r.y;
    const float pts2 = r.z;

    float Aa[3], W00[3], W01[3], W10[3], W11[3];
    uint4 g[3][4];

    #pragma unroll
    for (int p = 0; p < 3; ++p) {
        // plane 0 samples (y,z); plane 1 (x,z); plane 2 (x,y)
        const float sx = (p == 0) ? pts1 : pts0;
        const float sy = (p == 2) ? pts1 : pts2;
        const float pp = (p == 0) ? pts0 : ((p == 1) ? pts1 : pts2);

        const float ix = reflectf(sx);
        const float iy = reflectf(sy);
        const float x0f = floorf(ix), y0f = floorf(iy);
        const float wx = ix - x0f, wy = iy - y0f;
        int x0 = (int)x0f; x0 = min(max(x0, 0), RES - 1);
        int y0 = (int)y0f; y0 = min(max(y0, 0), RES - 1);
        const int x1 = min(x0 + 1, RES - 1);
        const int y1 = min(y0 + 1, RES - 1);
        W00[p] = (1.0f - wx) * (1.0f - wy);
        W01[p] = wx * (1.0f - wy);
        W10[p] = (1.0f - wx) * wy;
        W11[p] = wx * wy;
        // phase in revolutions: (pts+0.5)*(fr+0.5)/512 -> v_cos(2*pi*rev)
        Aa[p] = (pp + 0.5f) * (1.0f / 512.0f);

        const int rowbase = p * (RES * RES);
        const int o00 = (rowbase + y0 * RES + x0) * NPK + c * 4;
        const int o01 = (rowbase + y0 * RES + x1) * NPK + c * 4;
        const int o10 = (rowbase + y1 * RES + x0) * NPK + c * 4;
        const int o11 = (rowbase + y1 * RES + x1) * NPK + c * 4;
        g[p][0] = *(const uint4*)(grid + o00);
        g[p][1] = *(const uint4*)(grid + o01);
        g[p][2] = *(const uint4*)(grid + o10);
        g[p][3] = *(const uint4*)(grid + o11);
    }

    float acc = 0.0f;
    #pragma unroll
    for (int p = 0; p < 3; ++p) {
        const unsigned int w0[4] = {g[p][0].x, g[p][0].y, g[p][0].z, g[p][0].w};
        const unsigned int w1[4] = {g[p][1].x, g[p][1].y, g[p][1].z, g[p][1].w};
        const unsigned int w2[4] = {g[p][2].x, g[p][2].y, g[p][2].z, g[p][2].w};
        const unsigned int w3[4] = {g[p][3].x, g[p][3].y, g[p][3].z, g[p][3].w};
        const float w00 = W00[p], w01 = W01[p], w10 = W10[p], w11 = W11[p];
        const float A = Aa[p];

        #pragma unroll
        for (int jj = 0; jj < 4; ++jj) {
            const float clo = w00 * bf16_lo(w0[jj]) + w01 * bf16_lo(w1[jj])
                            + w10 * bf16_lo(w2[jj]) + w11 * bf16_lo(w3[jj]);
            const float chi = w00 * bf16_hi(w0[jj]) + w01 * bf16_hi(w1[jj])
                            + w10 * bf16_hi(w2[jj]) + w11 * bf16_hi(w3[jj]);
            const float rl = __builtin_amdgcn_fractf(A * frp[2 * jj + 0]);
            const float rh = __builtin_amdgcn_fractf(A * frp[2 * jj + 1]);
            acc += clo * __builtin_amdgcn_cosf(rl);
            acc += chi * __builtin_amdgcn_cosf(rh);
        }
    }

    __builtin_nontemporal_store(2.0f * acc, &out[(size_t)i * NC + c]);
}

// Fallback (no workspace): direct f32 channel-major gather.
__global__ __launch_bounds__(256) void fg_main_f32(
    const float* __restrict__ coords,
    const float* __restrict__ grid,
    const float* __restrict__ freqs,
    float* __restrict__ out, int n)
{
    const int t = threadIdx.x;
    const int c = t & 15;
    const int i = blockIdx.x * 16 + (t >> 4);
    if (i >= n) return;

    float frp[8];
    #pragma unroll
    for (int j = 0; j < 8; ++j) {
        float f = fminf(fmaxf(freqs[c * 8 + j], 0.0f), 1.0f);
        frp[j] = __builtin_amdgcn_exp2f(f * 8.0f) - 0.5f;
    }
    const float c0 = coords[3 * (size_t)i + 0];
    const float c1 = coords[3 * (size_t)i + 1];
    const float c2 = coords[3 * (size_t)i + 2];
    const float pts0 = (c0 + 1.0f) * 127.5f;
    const float pts1 = (c1 + 1.0f) * 127.5f;
    const float pts2 = (c2 + 1.0f) * 127.5f;
    float acc = 0.0f;
    #pragma unroll
    for (int p = 0; p < 3; ++p) {
        const float sx = (p == 0) ? pts1 : pts0;
        const float sy = (p == 2) ? pts1 : pts2;
        const float pp = (p == 0) ? pts0 : ((p == 1) ? pts1 : pts2);
        const float ix = reflectf(sx);
        const float iy = reflectf(sy);
        const float x0f = floorf(ix), y0f = floorf(iy);
        const float wx = ix - x0f, wy = iy - y0f;
        int x0 = (int)x0f; x0 = min(max(x0, 0), RES - 1);
        int y0 = (int)y0f; y0 = min(max(y0, 0), RES - 1);
        const int x1 = min(x0 + 1, RES - 1);
        const int y1 = min(y0 + 1, RES - 1);
        const float w00 = (1.0f - wx) * (1.0f - wy);
        const float w01 = wx * (1.0f - wy);
        const float w10 = (1.0f - wx) * wy;
        const float w11 = wx * wy;
        const float A = (pp + 0.5f) * (1.0f / 512.0f);
        const size_t plane = (size_t)p * NCH * RES * RES;
        const int o00 = y0 * RES + x0, o01 = y0 * RES + x1;
        const int o10 = y1 * RES + x0, o11 = y1 * RES + x1;
        #pragma unroll
        for (int j = 0; j < 8; ++j) {
            const float* gq = grid + plane + (size_t)(c * 8 + j) * (RES * RES);
            const float coef = w00 * gq[o00] + w01 * gq[o01]
                             + w10 * gq[o10] + w11 * gq[o11];
            const float rr = __builtin_amdgcn_fractf(A * frp[j]);
            acc += coef * __builtin_amdgcn_cosf(rr);
        }
    }
    out[(size_t)i * NC + c] = 2.0f * acc;
}

extern "C" void kernel_launch(void* const* d_in, const int* in_sizes, int n_in,
                              void* d_out, int out_size, void* d_ws, size_t ws_size,
                              hipStream_t stream)
{
    const float* coords = (const float*)d_in[0];
    const float* grid   = (const float*)d_in[1];
    const float* freqs  = (const float*)d_in[2];
    float* out = (float*)d_out;
    const int n = in_sizes[0] / 3;

    // Workspace layout (all 16B-aligned)
    const size_t gridT_b  = (size_t)3 * RES * RES * NPK * sizeof(unsigned); // 50.33 MB
    const size_t hist_b   = (size_t)NBINS * sizeof(unsigned);
    const size_t frp_b    = 128 * sizeof(float);
    const size_t rec_b    = (size_t)n * sizeof(float4);
    const size_t need = gridT_b + 2 * hist_b + frp_b + rec_b;

    const int blocks = (n + 15) / 16;

    if (ws_size >= need) {
        char* ws = (char*)d_ws;
        unsigned* gridT  = (unsigned*)ws;                 ws += gridT_b;
        unsigned* hist   = (unsigned*)ws;                 ws += hist_b;
        unsigned* cursor = (unsigned*)ws;                 ws += hist_b;
        float*    frp    = (float*)ws;                    ws += frp_b;
        float4*   rec    = (float4*)ws;

        (void)hipMemsetAsync(hist, 0, hist_b, stream);
        hipLaunchKernelGGL(fg_transpose_hist, dim3(4, RES, 3), dim3(256), 0, stream,
                           grid, gridT, coords, hist, n);
        hipLaunchKernelGGL(fg_scan, dim3(1), dim3(256), 0, stream,
                           hist, cursor, freqs, frp);
        hipLaunchKernelGGL(fg_scatter, dim3((n + 255) / 256), dim3(256), 0, stream,
                           coords, cursor, rec, n);
        hipLaunchKernelGGL(fg_main_bf16, dim3(blocks), dim3(256), 0, stream,
                           gridT, frp, rec, out, n);
    } else {
        hipLaunchKernelGGL(fg_main_f32, dim3(blocks), dim3(256), 0, stream,
                           coords, grid, freqs, out, n);
    }
}